// Round 1
// baseline (56.121 us; speedup 1.0000x reference)
//
#include <hip/hip_runtime.h>

// VQWeightedAvgPool: out[b,d] = sum_l w[b,l] * feat[b, N-1, l, d]
// w[b,l] = 1 / (n_seg_b * seg_len_b(l)) for l < len_b, else 0.
// Shapes: feat (B=16, N=13, L=2048, D=768) f32; lengths (B,) int; vq (B, L, 2) int.

#define L_SEQ 2048
#define D_DIM 768
#define N_DIM 13
#define BLK_A 256
#define PER_A (L_SEQ / BLK_A)   // 8 positions per thread
#define LT 16                    // L-rows per pooling block
#define TILES_PER_B (L_SEQ / LT) // 128

// ---------------- Kernel A: per-batch segment weights ----------------
__global__ __launch_bounds__(BLK_A) void vq_weights_kernel(
    const int* __restrict__ lengths,
    const int* __restrict__ vq,
    float* __restrict__ w) {
  __shared__ int s_seg[L_SEQ];   // inclusive cumsum of boundary (= seg_id + 1)
  __shared__ int s_cnt[L_SEQ];   // per-segment valid counts
  __shared__ int s_wsum[4];

  const int b = blockIdx.x;
  const int tid = threadIdx.x;
  const int lane = tid & 63;
  const int wid = tid >> 6;
  const int len = lengths[b];
  const int* vqb = vq + (size_t)b * L_SEQ * 2;

  // boundary flags + per-thread local inclusive prefix
  int flags[PER_A];
  const int base = tid * PER_A;
  int lsum = 0;
#pragma unroll
  for (int i = 0; i < PER_A; ++i) {
    const int l = base + i;
    int bd = 0;
    if (l < len) {
      if (l == 0)
        bd = 1;
      else
        bd = (vqb[2 * l] != vqb[2 * l - 2]) || (vqb[2 * l + 1] != vqb[2 * l - 1]);
    }
    lsum += bd;
    flags[i] = lsum;
  }

  // wave-level inclusive scan of per-thread totals
  int v = lsum;
  for (int off = 1; off < 64; off <<= 1) {
    int n = __shfl_up(v, off, 64);
    if (lane >= off) v += n;
  }
  if (lane == 63) s_wsum[wid] = v;
  __syncthreads();

  int woff = 0;
#pragma unroll
  for (int i = 0; i < 4; ++i)
    if (i < wid) woff += s_wsum[i];
  const int nseg = s_wsum[0] + s_wsum[1] + s_wsum[2] + s_wsum[3];
  const int excl = woff + (v - lsum);  // exclusive prefix for this thread's chunk

#pragma unroll
  for (int i = 0; i < PER_A; ++i) s_seg[base + i] = excl + flags[i];
  for (int l = tid; l < L_SEQ; l += BLK_A) s_cnt[l] = 0;
  __syncthreads();

  for (int l = tid; l < L_SEQ; l += BLK_A)
    if (l < len) atomicAdd(&s_cnt[s_seg[l] - 1], 1);
  __syncthreads();

  const float nsegf = (float)nseg;
  for (int l = tid; l < L_SEQ; l += BLK_A) {
    float wv = 0.0f;
    if (l < len) {
      const float denom = fmaxf(nsegf * (float)s_cnt[s_seg[l] - 1], 1.0f);
      wv = 1.0f / denom;
    }
    w[(size_t)b * L_SEQ + l] = wv;
  }
}

// ---------------- Kernel B: weighted pooling over L ----------------
// 192 threads: thread t owns float4 at d = 4*t (768 = 192*4).
__global__ __launch_bounds__(192) void vq_pool_kernel(
    const float* __restrict__ feat,
    const float* __restrict__ w,
    float* __restrict__ out) {
  const int tile = blockIdx.x;
  const int b = tile / TILES_PER_B;
  const int t = tile % TILES_PER_B;
  const int l0 = t * LT;
  const int tid = threadIdx.x;

  const float* base =
      feat + (((size_t)b * N_DIM + (N_DIM - 1)) * L_SEQ + l0) * D_DIM;
  const float* wb = w + (size_t)b * L_SEQ + l0;

  float4 acc = make_float4(0.f, 0.f, 0.f, 0.f);
#pragma unroll
  for (int i = 0; i < LT; ++i) {
    const float wl = wb[i];
    if (wl != 0.0f) {  // wave-uniform: skips tiles past len_b entirely
      const float4 vx = *(const float4*)(base + (size_t)i * D_DIM + tid * 4);
      acc.x += wl * vx.x;
      acc.y += wl * vx.y;
      acc.z += wl * vx.z;
      acc.w += wl * vx.w;
    }
  }

  float* o = out + (size_t)b * D_DIM + tid * 4;
  atomicAdd(o + 0, acc.x);
  atomicAdd(o + 1, acc.y);
  atomicAdd(o + 2, acc.z);
  atomicAdd(o + 3, acc.w);
}

extern "C" void kernel_launch(void* const* d_in, const int* in_sizes, int n_in,
                              void* d_out, int out_size, void* d_ws, size_t ws_size,
                              hipStream_t stream) {
  const float* feat = (const float*)d_in[0];
  const int* lengths = (const int*)d_in[1];
  const int* vq = (const int*)d_in[2];
  float* out = (float*)d_out;
  float* w = (float*)d_ws;  // B*L floats = 128 KiB

  const int B = in_sizes[1];  // 16

  hipMemsetAsync(d_out, 0, (size_t)out_size * sizeof(float), stream);
  vq_weights_kernel<<<B, BLK_A, 0, stream>>>(lengths, vq, w);
  vq_pool_kernel<<<B * TILES_PER_B, 192, 0, stream>>>(feat, w, out);
}

// Round 2
// 34.588 us; speedup vs baseline: 1.6226x; 1.6226x over previous
//
#include <hip/hip_runtime.h>

// VQWeightedAvgPool: out[b,d] = sum_l w[b,l] * feat[b, N-1, l, d]
// w[b,l] = 1 / (n_seg_b * seg_len_b(l)) for l < len_b, else 0.
// Shapes: feat (B=16, N=13, L=2048, D=768) f32; lengths (B,) int; vq (B, L, 2) int.

#define L_SEQ 2048
#define D_DIM 768
#define N_DIM 13
#define BLK_A 256
#define PER_A (L_SEQ / BLK_A)    // 8 positions per thread
#define LT 32                    // L-rows per pooling block
#define TILES_PER_B (L_SEQ / LT) // 64

// ---------------- Kernel A: per-batch segment weights (+ zero output) -------
__global__ __launch_bounds__(BLK_A) void vq_weights_kernel(
    const int* __restrict__ lengths,
    const int* __restrict__ vq,
    float* __restrict__ w,
    float* __restrict__ out) {
  __shared__ int s_seg[L_SEQ];   // inclusive cumsum of boundary (= seg_id + 1)
  __shared__ int s_cnt[L_SEQ];   // per-segment valid counts
  __shared__ int s_wsum[4];

  const int b = blockIdx.x;
  const int tid = threadIdx.x;
  const int lane = tid & 63;
  const int wid = tid >> 6;
  const int len = lengths[b];
  const int* vqb = vq + (size_t)b * L_SEQ * 2;

  // zero this batch's output slice (replaces hipMemsetAsync launch)
  for (int d = tid; d < D_DIM; d += BLK_A) out[(size_t)b * D_DIM + d] = 0.0f;

  // boundary flags + per-thread local inclusive prefix
  int flags[PER_A];
  const int base = tid * PER_A;
  int lsum = 0;
#pragma unroll
  for (int i = 0; i < PER_A; ++i) {
    const int l = base + i;
    int bd = 0;
    if (l < len) {
      if (l == 0)
        bd = 1;
      else
        bd = (vqb[2 * l] != vqb[2 * l - 2]) || (vqb[2 * l + 1] != vqb[2 * l - 1]);
    }
    lsum += bd;
    flags[i] = lsum;
  }

  // wave-level inclusive scan of per-thread totals
  int v = lsum;
  for (int off = 1; off < 64; off <<= 1) {
    int n = __shfl_up(v, off, 64);
    if (lane >= off) v += n;
  }
  if (lane == 63) s_wsum[wid] = v;
  __syncthreads();

  int woff = 0;
#pragma unroll
  for (int i = 0; i < 4; ++i)
    if (i < wid) woff += s_wsum[i];
  const int nseg = s_wsum[0] + s_wsum[1] + s_wsum[2] + s_wsum[3];
  const int excl = woff + (v - lsum);  // exclusive prefix for this thread's chunk

#pragma unroll
  for (int i = 0; i < PER_A; ++i) s_seg[base + i] = excl + flags[i];
  for (int l = tid; l < L_SEQ; l += BLK_A) s_cnt[l] = 0;
  __syncthreads();

  for (int l = tid; l < L_SEQ; l += BLK_A)
    if (l < len) atomicAdd(&s_cnt[s_seg[l] - 1], 1);
  __syncthreads();

  const float nsegf = (float)nseg;
  for (int l = tid; l < L_SEQ; l += BLK_A) {
    float wv = 0.0f;
    if (l < len) {
      const float denom = fmaxf(nsegf * (float)s_cnt[s_seg[l] - 1], 1.0f);
      wv = 1.0f / denom;
    }
    w[(size_t)b * L_SEQ + l] = wv;
  }
}

// ---------------- Kernel B: weighted pooling over L ----------------
// 192 threads: thread t owns float4 at d = 4*t (768 = 192*4).
__global__ __launch_bounds__(192) void vq_pool_kernel(
    const float* __restrict__ feat,
    const float* __restrict__ w,
    float* __restrict__ out) {
  const int tile = blockIdx.x;
  const int b = tile / TILES_PER_B;
  const int t = tile % TILES_PER_B;
  const int l0 = t * LT;
  const int tid = threadIdx.x;

  const float* base =
      feat + (((size_t)b * N_DIM + (N_DIM - 1)) * L_SEQ + l0) * D_DIM;
  const float* wb = w + (size_t)b * L_SEQ + l0;

  // Load all 32 weights first (uniform across lanes), one wave-uniform skip.
  float wl[LT];
  const float4* wb4 = (const float4*)wb;  // l0*4B = 128B-aligned
  bool any = false;
#pragma unroll
  for (int i = 0; i < LT / 4; ++i) {
    const float4 wv = wb4[i];
    wl[4 * i + 0] = wv.x;
    wl[4 * i + 1] = wv.y;
    wl[4 * i + 2] = wv.z;
    wl[4 * i + 3] = wv.w;
    any = any || (wv.x != 0.f) || (wv.y != 0.f) || (wv.z != 0.f) || (wv.w != 0.f);
  }
  if (!any) return;  // tile fully past len_b

  // Unconditional row loads: 32 independent float4 loads -> deep ILP.
  float4 acc = make_float4(0.f, 0.f, 0.f, 0.f);
#pragma unroll
  for (int i = 0; i < LT; ++i) {
    const float4 vx = *(const float4*)(base + (size_t)i * D_DIM + tid * 4);
    acc.x += wl[i] * vx.x;
    acc.y += wl[i] * vx.y;
    acc.z += wl[i] * vx.z;
    acc.w += wl[i] * vx.w;
  }

  float* o = out + (size_t)b * D_DIM + tid * 4;
  atomicAdd(o + 0, acc.x);
  atomicAdd(o + 1, acc.y);
  atomicAdd(o + 2, acc.z);
  atomicAdd(o + 3, acc.w);
}

extern "C" void kernel_launch(void* const* d_in, const int* in_sizes, int n_in,
                              void* d_out, int out_size, void* d_ws, size_t ws_size,
                              hipStream_t stream) {
  const float* feat = (const float*)d_in[0];
  const int* lengths = (const int*)d_in[1];
  const int* vq = (const int*)d_in[2];
  float* out = (float*)d_out;
  float* w = (float*)d_ws;  // B*L floats = 128 KiB

  const int B = in_sizes[1];  // 16

  vq_weights_kernel<<<B, BLK_A, 0, stream>>>(lengths, vq, w, out);
  vq_pool_kernel<<<B * TILES_PER_B, 192, 0, stream>>>(feat, w, out);
}

// Round 3
// 27.419 us; speedup vs baseline: 2.0468x; 1.2615x over previous
//
#include <hip/hip_runtime.h>

// VQWeightedAvgPool: out[b,d] = sum_l w[b,l] * feat[b, N-1, l, d]
// w[b,l] = 1 / (n_seg_b * seg_len_b(l)) for l < len_b, else 0.
// feat (B=16, N=13, L=2048, D=768) f32; lengths (B,) int; vq (B, L, 2) int.

#define L_SEQ 2048
#define D_DIM 768
#define N_DIM 13
#define BLK_A 256
#define PER_A 8                  // 2048 / 256
#define LT 32                    // L-rows per tile
#define MAX_TILES (L_SEQ / LT)   // 64
#define SUBS 32                  // pooling blocks per batch

// ---------------- Kernel A: per-batch segment weights (+ zero out, + counts)
__global__ __launch_bounds__(BLK_A) void vq_weights_kernel(
    const int* __restrict__ lengths,
    const int* __restrict__ vq,
    float* __restrict__ w,
    int* __restrict__ cnt,
    float* __restrict__ out) {
  __shared__ int s_seg[L_SEQ];   // inclusive cumsum of boundary (= seg_id + 1)
  __shared__ int s_cnt[L_SEQ];   // per-segment valid counts
  __shared__ int s_wsum[4];

  const int b = blockIdx.x;
  const int tid = threadIdx.x;
  const int lane = tid & 63;
  const int wid = tid >> 6;
  const int len = lengths[b];
  const int* vqb = vq + (size_t)b * L_SEQ * 2;

  // zero this batch's output slice (replaces hipMemsetAsync launch)
  for (int d = tid; d < D_DIM; d += BLK_A) out[(size_t)b * D_DIM + d] = 0.0f;

  // ---- vectorized pair loads: thread t owns l in [8t, 8t+8) ----
  int4 q[4];
  const int4* v4 = (const int4*)vqb;
#pragma unroll
  for (int i = 0; i < 4; ++i) q[i] = v4[4 * tid + i];
  int px = 0, py = 0;
  if (tid > 0) {
    const int2 pp = *(const int2*)(vqb + 16 * tid - 2);  // pair of l = 8t-1
    px = pp.x; py = pp.y;
  }
  int cx[PER_A], cy[PER_A];
  cx[0] = q[0].x; cy[0] = q[0].y; cx[1] = q[0].z; cy[1] = q[0].w;
  cx[2] = q[1].x; cy[2] = q[1].y; cx[3] = q[1].z; cy[3] = q[1].w;
  cx[4] = q[2].x; cy[4] = q[2].y; cx[5] = q[2].z; cy[5] = q[2].w;
  cx[6] = q[3].x; cy[6] = q[3].y; cx[7] = q[3].z; cy[7] = q[3].w;

  // boundary flags + per-thread local inclusive prefix
  int flags[PER_A];
  const int base = tid * PER_A;
  int lsum = 0;
#pragma unroll
  for (int i = 0; i < PER_A; ++i) {
    const int l = base + i;
    int bd = 0;
    if (l < len) {
      if (l == 0) {
        bd = 1;
      } else {
        const int prevx = (i == 0) ? px : cx[i - 1];
        const int prevy = (i == 0) ? py : cy[i - 1];
        bd = (cx[i] != prevx) || (cy[i] != prevy);
      }
    }
    lsum += bd;
    flags[i] = lsum;
  }

  // wave-level inclusive scan of per-thread totals
  int v = lsum;
  for (int off = 1; off < 64; off <<= 1) {
    int n = __shfl_up(v, off, 64);
    if (lane >= off) v += n;
  }
  if (lane == 63) s_wsum[wid] = v;
  __syncthreads();

  int woff = 0;
#pragma unroll
  for (int i = 0; i < 4; ++i)
    if (i < wid) woff += s_wsum[i];
  const int nseg = s_wsum[0] + s_wsum[1] + s_wsum[2] + s_wsum[3];
  const int excl = woff + (v - lsum);  // exclusive prefix for this thread's chunk

#pragma unroll
  for (int i = 0; i < PER_A; ++i) s_seg[base + i] = excl + flags[i];
  for (int l = tid; l < L_SEQ; l += BLK_A) s_cnt[l] = 0;
  __syncthreads();

  for (int l = tid; l < L_SEQ; l += BLK_A)
    if (l < len) atomicAdd(&s_cnt[s_seg[l] - 1], 1);
  __syncthreads();

  const float nsegf = (float)nseg;
  for (int l = tid; l < L_SEQ; l += BLK_A) {
    float wv = 0.0f;
    if (l < len) {
      const float denom = fmaxf(nsegf * (float)s_cnt[s_seg[l] - 1], 1.0f);
      wv = 1.0f / denom;
    }
    w[(size_t)b * L_SEQ + l] = wv;
  }

  if (tid == 0) {
    int c = (len + LT - 1) / LT;
    if (c > MAX_TILES) c = MAX_TILES;
    if (c < 1) c = 1;
    cnt[b] = c;
  }
}

// ---------------- Kernel B: weighted pooling over L ----------------
// 512 blocks: (b = blk>>5, sub = blk&31). Block handles valid tiles
// t = sub, sub+32, ... < cnt[b]; accumulates in regs; ONE atomic flush.
// 192 threads: thread owns float4 at d = 4*tid (768 = 192*4).
__global__ __launch_bounds__(192) void vq_pool_kernel(
    const float* __restrict__ feat,
    const float* __restrict__ w,
    const int* __restrict__ cnt,
    float* __restrict__ out) {
  const int b = blockIdx.x >> 5;
  const int sub = blockIdx.x & (SUBS - 1);
  const int tid = threadIdx.x;
  const int nt = cnt[b];

  const float* fb = feat + ((size_t)b * N_DIM + (N_DIM - 1)) * L_SEQ * D_DIM;
  const float* wb = w + (size_t)b * L_SEQ;

  float4 acc = make_float4(0.f, 0.f, 0.f, 0.f);
  for (int t = sub; t < nt; t += SUBS) {
    const int l0 = t * LT;
    // tile weights (uniform across lanes); trailing zeros handle len tail
    const float4* wb4 = (const float4*)(wb + l0);
    float wl[LT];
#pragma unroll
    for (int i = 0; i < LT / 4; ++i) {
      const float4 wv = wb4[i];
      wl[4 * i + 0] = wv.x;
      wl[4 * i + 1] = wv.y;
      wl[4 * i + 2] = wv.z;
      wl[4 * i + 3] = wv.w;
    }
    // 32 independent unconditional float4 row loads -> deep MLP
    const float* basep = fb + (size_t)l0 * D_DIM + tid * 4;
#pragma unroll
    for (int i = 0; i < LT; ++i) {
      const float4 vx = *(const float4*)(basep + (size_t)i * D_DIM);
      acc.x += wl[i] * vx.x;
      acc.y += wl[i] * vx.y;
      acc.z += wl[i] * vx.z;
      acc.w += wl[i] * vx.w;
    }
  }

  float* o = out + (size_t)b * D_DIM + tid * 4;
  atomicAdd(o + 0, acc.x);
  atomicAdd(o + 1, acc.y);
  atomicAdd(o + 2, acc.z);
  atomicAdd(o + 3, acc.w);
}

extern "C" void kernel_launch(void* const* d_in, const int* in_sizes, int n_in,
                              void* d_out, int out_size, void* d_ws, size_t ws_size,
                              hipStream_t stream) {
  const float* feat = (const float*)d_in[0];
  const int* lengths = (const int*)d_in[1];
  const int* vq = (const int*)d_in[2];
  float* out = (float*)d_out;
  float* w = (float*)d_ws;                    // B*L floats = 128 KiB
  int* cnt = (int*)(w + (size_t)16 * L_SEQ);  // 16 ints after w

  const int B = in_sizes[1];  // 16

  vq_weights_kernel<<<B, BLK_A, 0, stream>>>(lengths, vq, w, cnt, out);
  vq_pool_kernel<<<B * SUBS, 192, 0, stream>>>(feat, w, cnt, out);
}